// Round 4
// baseline (1110.008 us; speedup 1.0000x reference)
//
#include <hip/hip_runtime.h>
#include <hip/hip_bf16.h>
#include <math.h>

#define NN 50000
#define NE 400000
#define NM 3
#define IND 128
#define OUTD 64
#define NH 4
#define HO 256          // NH*OUTD
#define EPSBN 1e-5f
#define SLOPE 0.2f

// ---------- bf16 helpers (RNE) ----------
__device__ __forceinline__ unsigned short f2bf(float f) {
    unsigned u = __float_as_uint(f);
    unsigned r = (u + 0x7FFFu + ((u >> 16) & 1u)) >> 16;
    return (unsigned short)r;
}
__device__ __forceinline__ float bf2f(unsigned short b) {
    return __uint_as_float(((unsigned)b) << 16);
}

// ---------- init: zero accumulated buffers ----------
__global__ __launch_bounds__(256) void k_init(int* __restrict__ deg3,
                                              float* __restrict__ asum3,
                                              float* __restrict__ scal3,
                                              int* __restrict__ gcur) {
    size_t i = (size_t)blockIdx.x * blockDim.x + threadIdx.x;
    if (i < (size_t)NM * NN) { deg3[i] = 0; asum3[i] = 0.f; }
    if (i < NM * 16) scal3[i] = 0.f;
    if (i < NM) gcur[i] = 0;
}

// ---------- fused: BN stats + degree + raw log1p sum per destination ----------
__global__ __launch_bounds__(256) void k_bn_deg(const float* __restrict__ eattr,
                                                const int* __restrict__ ei,
                                                float* __restrict__ scal3,
                                                int* __restrict__ deg3,
                                                float* __restrict__ asum3) {
    int m = blockIdx.y;
    int e = blockIdx.x * blockDim.x + threadIdx.x;
    float s1 = 0.f, s2 = 0.f;
    if (e < NE) {
        const float* ea = eattr + (size_t)m * NE;
        const int* dst = ei + (size_t)m * 2 * NE + NE;
        float v = log1pf(ea[e]);
        int d = dst[e];
        atomicAdd(&deg3[(size_t)m * NN + d], 1);
        atomicAdd(&asum3[(size_t)m * NN + d], v);   // RAW log1p sum
        s1 = v; s2 = v * v;
    }
    #pragma unroll
    for (int o = 32; o > 0; o >>= 1) {
        s1 += __shfl_down(s1, o);
        s2 += __shfl_down(s2, o);
    }
    if ((threadIdx.x & 63) == 0) {
        atomicAdd(&scal3[m * 16 + 0], s1);
        atomicAdd(&scal3[m * 16 + 1], s2);
    }
}

__global__ __launch_bounds__(64) void k_bn_fin(const float* __restrict__ gamma,
                                               const float* __restrict__ beta,
                                               const float* __restrict__ lin_edge,
                                               const float* __restrict__ att_edge,
                                               float* __restrict__ scal3) {
    int m = blockIdx.x;
    int t = threadIdx.x;
    float* scal = scal3 + m * 16;
    if (t == 0) {
        float mu = scal[0] / (float)NE;
        float var = scal[1] / (float)NE - mu * mu;
        float sc = gamma[m] * rsqrtf(var + EPSBN);
        scal[2] = sc;
        scal[3] = beta[m] - mu * sc;
    }
    if (t < 4) {
        const float* le = lin_edge + (size_t)m * HO;
        const float* ae = att_edge + (size_t)m * HO;
        float acc = 0.f;
        for (int c = 0; c < 64; ++c)
            acc += le[t * 64 + c] * ae[t * 64 + c];
        scal[4 + t] = acc;
    }
}

// ---------- parallel range allocator (replaces ordered scan) ----------
// Ranges are disjoint chunks of [0, NE) per metapath; order is irrelevant to
// consumers (passC uses start[d] .. start[d]+deg[d]).
__global__ __launch_bounds__(256) void k_offsets(const int* __restrict__ deg3,
                                                 int* __restrict__ start3,
                                                 int* __restrict__ cur3,
                                                 int* __restrict__ gcur) {
    int m = blockIdx.y;
    int i = blockIdx.x * blockDim.x + threadIdx.x;   // node id
    int lane = threadIdx.x & 63;
    int d = (i < NN) ? deg3[(size_t)m * NN + i] : 0;
    // wave inclusive scan
    int inc = d;
    #pragma unroll
    for (int o = 1; o < 64; o <<= 1) {
        int v = __shfl_up(inc, o);
        if (lane >= o) inc += v;
    }
    int total = __shfl(inc, 63);
    int base = 0;
    if (lane == 63 && total > 0) base = atomicAdd(&gcur[m], total);
    base = __shfl(base, 63);
    int excl = inc - d;
    if (i < NN) {
        start3[(size_t)m * NN + i] = base + excl;
        cur3[(size_t)m * NN + i] = base + excl;
    }
}

// ---------- GEMM: h(bf16) = x @ W[m], fused a_src/a_dst epilogue ----------
__global__ __launch_bounds__(256) void k_gemm(const float* __restrict__ x,
                                              const float* __restrict__ Wm,
                                              const float* __restrict__ att_s,
                                              const float* __restrict__ att_d,
                                              unsigned short* __restrict__ hbf,
                                              float* __restrict__ asn,
                                              float* __restrict__ adn) {
    __shared__ float As[128 * 68];  // [k][row], pad 68
    __shared__ float Bs[128 * 68];  // [k][col], pad 68
    int t = threadIdx.x;
    int row0 = blockIdx.x * 64;
    int col0 = blockIdx.y * 64;   // = head * 64
    #pragma unroll
    for (int i = 0; i < 32; ++i) {
        int e = i * 256 + t;
        int r = e >> 7, k = e & 127;
        float v = (row0 + r < NN) ? x[(size_t)(row0 + r) * IND + k] : 0.f;
        As[k * 68 + r] = v;
    }
    #pragma unroll
    for (int i = 0; i < 32; ++i) {
        int e = i * 256 + t;
        int k = e >> 6, c = e & 63;
        Bs[k * 68 + c] = Wm[k * HO + col0 + c];
    }
    __syncthreads();
    int tx = t & 15, ty = t >> 4;
    float acc[4][4];
    #pragma unroll
    for (int i = 0; i < 4; ++i)
        #pragma unroll
        for (int j = 0; j < 4; ++j) acc[i][j] = 0.f;
    #pragma unroll 8
    for (int k = 0; k < 128; ++k) {
        float4 a4 = *(const float4*)&As[k * 68 + 4 * ty];
        float4 b4 = *(const float4*)&Bs[k * 68 + 4 * tx];
        float av[4] = {a4.x, a4.y, a4.z, a4.w};
        float bv[4] = {b4.x, b4.y, b4.z, b4.w};
        #pragma unroll
        for (int i = 0; i < 4; ++i)
            #pragma unroll
            for (int j = 0; j < 4; ++j)
                acc[i][j] = fmaf(av[i], bv[j], acc[i][j]);
    }
    // store h tile (bf16)
    #pragma unroll
    for (int i = 0; i < 4; ++i) {
        int r = row0 + 4 * ty + i;
        if (r < NN) {
            ushort4 o;
            o.x = f2bf(acc[i][0]); o.y = f2bf(acc[i][1]);
            o.z = f2bf(acc[i][2]); o.w = f2bf(acc[i][3]);
            *(ushort4*)&hbf[(size_t)r * HO + col0 + 4 * tx] = o;
        }
    }
    // fused per-node attention coefficients (fp32 acc)
    int hh = blockIdx.y;
    float as4[4], ad4[4];
    #pragma unroll
    for (int j = 0; j < 4; ++j) {
        as4[j] = att_s[col0 + 4 * tx + j];
        ad4[j] = att_d[col0 + 4 * tx + j];
    }
    #pragma unroll
    for (int i = 0; i < 4; ++i) {
        float s = 0.f, d = 0.f;
        #pragma unroll
        for (int j = 0; j < 4; ++j) {
            s = fmaf(acc[i][j], as4[j], s);
            d = fmaf(acc[i][j], ad4[j], d);
        }
        #pragma unroll
        for (int o = 8; o > 0; o >>= 1) {
            s += __shfl_xor(s, o, 16);
            d += __shfl_xor(d, o, 16);
        }
        int r = row0 + 4 * ty + i;
        if (tx == 0 && r < NN) {
            asn[r * 4 + hh] = s;
            adn[r * 4 + hh] = d;
        }
    }
}

// ---------- scatter: alpha -> exp(alpha), write CSR (src, ex4) ----------
__global__ __launch_bounds__(256) void k_scatter(const int* __restrict__ srcA,
                                                 const int* __restrict__ dstA,
                                                 const float* __restrict__ ea,
                                                 const float* __restrict__ scal,
                                                 const float* __restrict__ asn,
                                                 const float* __restrict__ adn,
                                                 int* __restrict__ cur,
                                                 int* __restrict__ csrc,
                                                 float* __restrict__ cex) {
    int e = blockIdx.x * blockDim.x + threadIdx.x;
    if (e >= NE) return;
    int s = srcA[e], d = dstA[e];
    float ev = log1pf(ea[e]) * scal[2] + scal[3];
    float4 as4 = *(const float4*)&asn[s * 4];
    float4 ad4 = *(const float4*)&adn[d * 4];
    float av[4] = {as4.x + ad4.x, as4.y + ad4.y, as4.z + ad4.z, as4.w + ad4.w};
    float ex[4];
    #pragma unroll
    for (int hh = 0; hh < NH; ++hh) {
        float a = av[hh] + ev * scal[4 + hh];
        a = (a >= 0.f) ? a : SLOPE * a;
        ex[hh] = expf(a);
    }
    int pos = atomicAdd(&cur[d], 1);
    csrc[pos] = s;
    *(float4*)&cex[(size_t)pos * 4] = make_float4(ex[0], ex[1], ex[2], ex[3]);
}

// ---------- pass C: wave per destination, register accumulate, no atomics ----------
__global__ __launch_bounds__(256) void k_passC(const int* __restrict__ start,
                                               const int* __restrict__ csrc,
                                               const float* __restrict__ cex,
                                               const unsigned short* __restrict__ hbf,
                                               const float* __restrict__ asn,
                                               const float* __restrict__ adn,
                                               const int* __restrict__ deg,
                                               const float* __restrict__ asum,
                                               const float* __restrict__ scal,
                                               const float* __restrict__ bias,
                                               float* __restrict__ zall,
                                               int mslice) {
    int lane = threadIdx.x & 63;
    int d = (int)((blockIdx.x * (size_t)blockDim.x + threadIdx.x) >> 6);
    if (d >= NN) return;
    // self-loop term: ev from RAW asum (affine BN applied here); deg==0 -> 0
    float4 as4 = *(const float4*)&asn[d * 4];
    float4 ad4 = *(const float4*)&adn[d * 4];
    float dg = (float)deg[d];
    float ev = (dg > 0.f) ? (asum[d] / dg) * scal[2] + scal[3] : 0.f;
    float av[4] = {as4.x + ad4.x, as4.y + ad4.y, as4.z + ad4.z, as4.w + ad4.w};
    float den[4], acc[4];
    const unsigned short* hd = &hbf[(size_t)d * HO];
    #pragma unroll
    for (int hh = 0; hh < NH; ++hh) {
        float a = av[hh] + ev * scal[4 + hh];
        a = (a >= 0.f) ? a : SLOPE * a;
        float exs = expf(a);
        den[hh] = exs;
        acc[hh] = exs * bf2f(hd[hh * 64 + lane]);
    }
    int p0 = start[d], p1 = p0 + deg[d];
    for (int p = p0; p < p1; ++p) {
        int s = csrc[p];                                  // wave-uniform broadcast
        float4 e4 = *(const float4*)&cex[(size_t)p * 4];  // broadcast
        const unsigned short* hs = &hbf[(size_t)s * HO];
        den[0] += e4.x; den[1] += e4.y; den[2] += e4.z; den[3] += e4.w;
        acc[0] = fmaf(e4.x, bf2f(hs[lane]), acc[0]);
        acc[1] = fmaf(e4.y, bf2f(hs[64 + lane]), acc[1]);
        acc[2] = fmaf(e4.z, bf2f(hs[128 + lane]), acc[2]);
        acc[3] = fmaf(e4.w, bf2f(hs[192 + lane]), acc[3]);
    }
    float z = 0.25f * (acc[0] / den[0] + acc[1] / den[1] +
                       acc[2] / den[2] + acc[3] / den[3]) + bias[lane];
    z = (z > 0.f) ? z : expm1f(z);
    zall[(size_t)d * 192 + mslice * 64 + lane] = z;
}

// ---------- semantic attention: sem_W column in VGPRs, z via LDS broadcast ----------
__global__ __launch_bounds__(256) void k_semantic(const float* __restrict__ zall,
                                                  const float* __restrict__ semW,
                                                  const float* __restrict__ semb,
                                                  const float* __restrict__ avec,
                                                  float* __restrict__ out) {
    __shared__ float zbuf[4][192];
    int t = threadIdx.x;
    int lane = t & 63;
    int wid = t >> 6;
    float wsc[64];
    #pragma unroll
    for (int k = 0; k < 64; ++k) wsc[k] = semW[k * 64 + lane];
    float sb = semb[lane];
    float av = avec[lane];
    int gw = blockIdx.x * 4 + wid;
    int nwv = gridDim.x * 4;
    for (int n = gw; n < NN; n += nwv) {
        float zm0 = zall[(size_t)n * 192 + lane];
        float zm1 = zall[(size_t)n * 192 + 64 + lane];
        float zm2 = zall[(size_t)n * 192 + 128 + lane];
        zbuf[wid][lane] = zm0;
        zbuf[wid][64 + lane] = zm1;
        zbuf[wid][128 + lane] = zm2;
        float sc3[3];
        #pragma unroll
        for (int m = 0; m < 3; ++m) {
            float a0 = sb, a1 = 0.f, a2 = 0.f, a3 = 0.f;
            #pragma unroll
            for (int k4 = 0; k4 < 16; ++k4) {
                float4 z4 = *(const float4*)&zbuf[wid][m * 64 + k4 * 4];
                a0 = fmaf(z4.x, wsc[k4 * 4 + 0], a0);
                a1 = fmaf(z4.y, wsc[k4 * 4 + 1], a1);
                a2 = fmaf(z4.z, wsc[k4 * 4 + 2], a2);
                a3 = fmaf(z4.w, wsc[k4 * 4 + 3], a3);
            }
            float wg = tanhf((a0 + a1) + (a2 + a3));
            float p = wg * av;
            #pragma unroll
            for (int o = 32; o > 0; o >>= 1) p += __shfl_xor(p, o);
            sc3[m] = p;
        }
        float mx = fmaxf(sc3[0], fmaxf(sc3[1], sc3[2]));
        float e0 = expf(sc3[0] - mx), e1 = expf(sc3[1] - mx), e2 = expf(sc3[2] - mx);
        float inv = 1.f / (e0 + e1 + e2);
        float b0 = e0 * inv, b1 = e1 * inv, b2 = e2 * inv;
        out[(size_t)n * 64 + lane] = b0 * zm0 + b1 * zm1 + b2 * zm2;
        if (lane < 3) {
            float b = (lane == 0) ? b0 : (lane == 1) ? b1 : b2;
            out[(size_t)NN * 64 + (size_t)n * 3 + lane] = b;
        }
    }
}

// ---------- host ----------
extern "C" void kernel_launch(void* const* d_in, const int* in_sizes, int n_in,
                              void* d_out, int out_size, void* d_ws, size_t ws_size,
                              hipStream_t stream) {
    (void)in_sizes; (void)n_in; (void)out_size; (void)ws_size;
    const float* x        = (const float*)d_in[0];
    const int*   ei       = (const int*)d_in[1];
    const float* eattr    = (const float*)d_in[2];
    const float* W        = (const float*)d_in[3];
    const float* att_src  = (const float*)d_in[4];
    const float* att_dst  = (const float*)d_in[5];
    const float* lin_edge = (const float*)d_in[6];
    const float* att_edge = (const float*)d_in[7];
    const float* bias     = (const float*)d_in[8];
    const float* bn_gamma = (const float*)d_in[9];
    const float* bn_beta  = (const float*)d_in[10];
    const float* sem_W    = (const float*)d_in[11];
    const float* sem_b    = (const float*)d_in[12];
    const float* attn_vec = (const float*)d_in[13];
    float* out = (float*)d_out;

    float* ws = (float*)d_ws;
    size_t o = 0;
    unsigned short* hbf = (unsigned short*)(ws + o); o += (size_t)NN * 128;  // 25.6 MB (bf16)
    float* zall   = ws + o; o += (size_t)NN * 192;   // 38.4 MB
    float* cex    = ws + o; o += (size_t)NE * 4;     //  6.4 MB
    int*   csrc   = (int*)(ws + o); o += (size_t)NE; //  1.6 MB
    float* asn    = ws + o; o += (size_t)NN * 4;
    float* adn    = ws + o; o += (size_t)NN * 4;
    int*   deg3   = (int*)(ws + o); o += (size_t)NM * NN;
    float* asum3  = ws + o; o += (size_t)NM * NN;
    int*   start3 = (int*)(ws + o); o += (size_t)NM * NN;
    int*   cur3   = (int*)(ws + o); o += (size_t)NM * NN;
    float* scal3  = ws + o; o += NM * 16;
    int*   gcur   = (int*)(ws + o); o += 16;
    // total ~77 MB

    k_init<<<((NM * NN) + 255) / 256, 256, 0, stream>>>(deg3, asum3, scal3, gcur);
    k_bn_deg<<<dim3((NE + 255) / 256, NM), 256, 0, stream>>>(eattr, ei, scal3, deg3, asum3);
    k_bn_fin<<<NM, 64, 0, stream>>>(bn_gamma, bn_beta, lin_edge, att_edge, scal3);
    k_offsets<<<dim3((NN + 255) / 256, NM), 256, 0, stream>>>(deg3, start3, cur3, gcur);

    for (int m = 0; m < NM; ++m) {
        const int* srcA = ei + (size_t)m * 2 * NE;
        const int* dstA = srcA + NE;
        const float* eam = eattr + (size_t)m * NE;

        k_gemm<<<dim3((NN + 63) / 64, NH), 256, 0, stream>>>(
            x, W + (size_t)m * IND * HO,
            att_src + (size_t)m * HO, att_dst + (size_t)m * HO,
            hbf, asn, adn);
        k_scatter<<<(NE + 255) / 256, 256, 0, stream>>>(
            srcA, dstA, eam, scal3 + m * 16, asn, adn,
            cur3 + (size_t)m * NN, csrc, cex);
        k_passC<<<((size_t)NN * 64 + 255) / 256, 256, 0, stream>>>(
            start3 + (size_t)m * NN, csrc, cex, hbf, asn, adn,
            deg3 + (size_t)m * NN, asum3 + (size_t)m * NN,
            scal3 + m * 16, bias + (size_t)m * 64, zall, m);
    }

    k_semantic<<<2048, 256, 0, stream>>>(zall, sem_W, sem_b, attn_vec, out);
}

// Round 11
// 759.392 us; speedup vs baseline: 1.4617x; 1.4617x over previous
//
#include <hip/hip_runtime.h>
#include <hip/hip_bf16.h>
#include <math.h>

#define NN 50000
#define NE 400000
#define NM 3
#define IND 128
#define OUTD 64
#define NH 4
#define HO 256          // NH*OUTD
#define EPSBN 1e-5f
#define SLOPE 0.2f
#define PB ((NE + 255) / 256)        // partial blocks per metapath = 1563
#define FIXS 8388608.0f              // 2^23 fixed-point scale for asum
#define FIXINV (1.0f / 8388608.0f)
#define PKMASK ((1ULL << 40) - 1ULL)

// ---------- bf16 helpers (RNE) ----------
__device__ __forceinline__ unsigned short f2bf(float f) {
    unsigned u = __float_as_uint(f);
    unsigned r = (u + 0x7FFFu + ((u >> 16) & 1u)) >> 16;
    return (unsigned short)r;
}
__device__ __forceinline__ float bf2f(unsigned short b) {
    return __uint_as_float(((unsigned)b) << 16);
}

// ---------- init: zero packed deg/asum + global cursors ----------
__global__ __launch_bounds__(256) void k_init(unsigned long long* __restrict__ pk,
                                              int* __restrict__ gcur) {
    size_t i = (size_t)blockIdx.x * blockDim.x + threadIdx.x;
    if (i < (size_t)NM * NN) pk[i] = 0ULL;
    if (i < 16) gcur[i] = 0;
}

// ---------- fused: BN partials + packed degree/asum atomic + per-m edge rank ----------
__global__ __launch_bounds__(256) void k_bn_deg(const float* __restrict__ eattr,
                                                const int* __restrict__ ei,
                                                unsigned long long* __restrict__ pk,
                                                int* __restrict__ rank3,
                                                float2* __restrict__ part3) {
    int m = blockIdx.y;
    int e = blockIdx.x * blockDim.x + threadIdx.x;
    float s1 = 0.f, s2 = 0.f;
    if (e < NE) {
        const float* ea = eattr + (size_t)m * NE;
        const int* dst = ei + (size_t)m * 2 * NE + NE;
        float v = log1pf(ea[e]);
        int d = dst[e];
        unsigned long long inc = (1ULL << 40) +
            (unsigned long long)(v * FIXS + 0.5f);
        unsigned long long old = atomicAdd(&pk[(size_t)m * NN + d], inc);
        rank3[(size_t)m * NE + e] = (int)(old >> 40);   // rank among same-dst edges, PER m
        s1 = v; s2 = v * v;
    }
    // block-level BN-stat reduction -> one plain store per block (no contention)
    #pragma unroll
    for (int o = 32; o > 0; o >>= 1) {
        s1 += __shfl_down(s1, o);
        s2 += __shfl_down(s2, o);
    }
    __shared__ float ls1[4], ls2[4];
    int t = threadIdx.x;
    if ((t & 63) == 0) { ls1[t >> 6] = s1; ls2[t >> 6] = s2; }
    __syncthreads();
    if (t == 0) {
        float a = (ls1[0] + ls1[1]) + (ls1[2] + ls1[3]);
        float b = (ls2[0] + ls2[1]) + (ls2[2] + ls2[3]);
        part3[(size_t)m * PB + blockIdx.x] = make_float2(a, b);
    }
}

// ---------- finalize BN scale/shift + edge-attention dot products ----------
__global__ __launch_bounds__(256) void k_bn_fin(const float* __restrict__ gamma,
                                                const float* __restrict__ beta,
                                                const float* __restrict__ lin_edge,
                                                const float* __restrict__ att_edge,
                                                const float2* __restrict__ part3,
                                                float* __restrict__ scal3) {
    int m = blockIdx.x;
    int t = threadIdx.x;
    float* scal = scal3 + m * 16;
    const float2* part = part3 + (size_t)m * PB;
    float s1 = 0.f, s2 = 0.f;
    for (int i = t; i < PB; i += 256) {
        float2 p = part[i];
        s1 += p.x; s2 += p.y;
    }
    #pragma unroll
    for (int o = 32; o > 0; o >>= 1) {
        s1 += __shfl_down(s1, o);
        s2 += __shfl_down(s2, o);
    }
    __shared__ float ls1[4], ls2[4];
    if ((t & 63) == 0) { ls1[t >> 6] = s1; ls2[t >> 6] = s2; }
    __syncthreads();
    if (t == 0) {
        float su = (ls1[0] + ls1[1]) + (ls1[2] + ls1[3]);
        float sq = (ls2[0] + ls2[1]) + (ls2[2] + ls2[3]);
        float mu = su / (float)NE;
        float var = sq / (float)NE - mu * mu;
        float sc = gamma[m] * rsqrtf(var + EPSBN);
        scal[2] = sc;
        scal[3] = beta[m] - mu * sc;
    }
    if (t < 4) {
        const float* le = lin_edge + (size_t)m * HO;
        const float* ae = att_edge + (size_t)m * HO;
        float acc = 0.f;
        for (int c = 0; c < 64; ++c)
            acc += le[t * 64 + c] * ae[t * 64 + c];
        scal[4 + t] = acc;
    }
}

// ---------- parallel range allocator (unordered disjoint CSR ranges) ----------
__global__ __launch_bounds__(256) void k_offsets(const unsigned long long* __restrict__ pk,
                                                 int* __restrict__ start3,
                                                 int* __restrict__ gcur) {
    int m = blockIdx.y;
    int i = blockIdx.x * blockDim.x + threadIdx.x;   // node id
    int lane = threadIdx.x & 63;
    int d = (i < NN) ? (int)(pk[(size_t)m * NN + i] >> 40) : 0;
    int inc = d;
    #pragma unroll
    for (int o = 1; o < 64; o <<= 1) {
        int v = __shfl_up(inc, o);
        if (lane >= o) inc += v;
    }
    int total = __shfl(inc, 63);
    int base = 0;
    if (lane == 63 && total > 0) base = atomicAdd(&gcur[m], total);
    base = __shfl(base, 63);
    if (i < NN) start3[(size_t)m * NN + i] = base + inc - d;
}

// ---------- GEMM: h(bf16) = x @ W[m], fused a_src/a_dst epilogue ----------
__global__ __launch_bounds__(256) void k_gemm(const float* __restrict__ x,
                                              const float* __restrict__ Wm,
                                              const float* __restrict__ att_s,
                                              const float* __restrict__ att_d,
                                              unsigned short* __restrict__ hbf,
                                              float* __restrict__ asn,
                                              float* __restrict__ adn) {
    __shared__ float As[128 * 68];  // [k][row], pad 68
    __shared__ float Bs[128 * 68];  // [k][col], pad 68
    int t = threadIdx.x;
    int row0 = blockIdx.x * 64;
    int col0 = blockIdx.y * 64;   // = head * 64
    #pragma unroll
    for (int i = 0; i < 32; ++i) {
        int e = i * 256 + t;
        int r = e >> 7, k = e & 127;
        float v = (row0 + r < NN) ? x[(size_t)(row0 + r) * IND + k] : 0.f;
        As[k * 68 + r] = v;
    }
    #pragma unroll
    for (int i = 0; i < 32; ++i) {
        int e = i * 256 + t;
        int k = e >> 6, c = e & 63;
        Bs[k * 68 + c] = Wm[k * HO + col0 + c];
    }
    __syncthreads();
    int tx = t & 15, ty = t >> 4;
    float acc[4][4];
    #pragma unroll
    for (int i = 0; i < 4; ++i)
        #pragma unroll
        for (int j = 0; j < 4; ++j) acc[i][j] = 0.f;
    #pragma unroll 8
    for (int k = 0; k < 128; ++k) {
        float4 a4 = *(const float4*)&As[k * 68 + 4 * ty];
        float4 b4 = *(const float4*)&Bs[k * 68 + 4 * tx];
        float av[4] = {a4.x, a4.y, a4.z, a4.w};
        float bv[4] = {b4.x, b4.y, b4.z, b4.w};
        #pragma unroll
        for (int i = 0; i < 4; ++i)
            #pragma unroll
            for (int j = 0; j < 4; ++j)
                acc[i][j] = fmaf(av[i], bv[j], acc[i][j]);
    }
    #pragma unroll
    for (int i = 0; i < 4; ++i) {
        int r = row0 + 4 * ty + i;
        if (r < NN) {
            ushort4 o;
            o.x = f2bf(acc[i][0]); o.y = f2bf(acc[i][1]);
            o.z = f2bf(acc[i][2]); o.w = f2bf(acc[i][3]);
            *(ushort4*)&hbf[(size_t)r * HO + col0 + 4 * tx] = o;
        }
    }
    int hh = blockIdx.y;
    float as4[4], ad4[4];
    #pragma unroll
    for (int j = 0; j < 4; ++j) {
        as4[j] = att_s[col0 + 4 * tx + j];
        ad4[j] = att_d[col0 + 4 * tx + j];
    }
    #pragma unroll
    for (int i = 0; i < 4; ++i) {
        float s = 0.f, d = 0.f;
        #pragma unroll
        for (int j = 0; j < 4; ++j) {
            s = fmaf(acc[i][j], as4[j], s);
            d = fmaf(acc[i][j], ad4[j], d);
        }
        #pragma unroll
        for (int o = 8; o > 0; o >>= 1) {
            s += __shfl_xor(s, o, 16);
            d += __shfl_xor(d, o, 16);
        }
        int r = row0 + 4 * ty + i;
        if (tx == 0 && r < NN) {
            asn[r * 4 + hh] = s;
            adn[r * 4 + hh] = d;
        }
    }
}

// ---------- scatter: alpha -> exp(alpha), slot = start[d] + rank[e], NO atomics ----------
__global__ __launch_bounds__(256) void k_scatter(const int* __restrict__ srcA,
                                                 const int* __restrict__ dstA,
                                                 const float* __restrict__ ea,
                                                 const float* __restrict__ scal,
                                                 const float* __restrict__ asn,
                                                 const float* __restrict__ adn,
                                                 const int* __restrict__ start,
                                                 const int* __restrict__ rank,
                                                 int* __restrict__ csrc,
                                                 float* __restrict__ cex) {
    int e = blockIdx.x * blockDim.x + threadIdx.x;
    if (e >= NE) return;
    int s = srcA[e], d = dstA[e];
    float ev = log1pf(ea[e]) * scal[2] + scal[3];
    float4 as4 = *(const float4*)&asn[s * 4];
    float4 ad4 = *(const float4*)&adn[d * 4];
    float av[4] = {as4.x + ad4.x, as4.y + ad4.y, as4.z + ad4.z, as4.w + ad4.w};
    float ex[4];
    #pragma unroll
    for (int hh = 0; hh < NH; ++hh) {
        float a = av[hh] + ev * scal[4 + hh];
        a = (a >= 0.f) ? a : SLOPE * a;
        ex[hh] = expf(a);
    }
    int pos = start[d] + rank[e];
    csrc[pos] = s;
    *(float4*)&cex[(size_t)pos * 4] = make_float4(ex[0], ex[1], ex[2], ex[3]);
}

// ---------- pass C: wave per destination, register accumulate, no atomics ----------
__global__ __launch_bounds__(256) void k_passC(const int* __restrict__ start,
                                               const int* __restrict__ csrc,
                                               const float* __restrict__ cex,
                                               const unsigned short* __restrict__ hbf,
                                               const float* __restrict__ asn,
                                               const float* __restrict__ adn,
                                               const unsigned long long* __restrict__ pk,
                                               const float* __restrict__ scal,
                                               const float* __restrict__ bias,
                                               float* __restrict__ zall,
                                               int mslice) {
    int lane = threadIdx.x & 63;
    int d = (int)((blockIdx.x * (size_t)blockDim.x + threadIdx.x) >> 6);
    if (d >= NN) return;
    unsigned long long pkd = pk[d];
    int dgi = (int)(pkd >> 40);
    float asum = (float)(pkd & PKMASK) * FIXINV;
    float4 as4 = *(const float4*)&asn[d * 4];
    float4 ad4 = *(const float4*)&adn[d * 4];
    float ev = (dgi > 0) ? (asum / (float)dgi) * scal[2] + scal[3] : 0.f;
    float av[4] = {as4.x + ad4.x, as4.y + ad4.y, as4.z + ad4.z, as4.w + ad4.w};
    float den[4], acc[4];
    const unsigned short* hd = &hbf[(size_t)d * HO];
    #pragma unroll
    for (int hh = 0; hh < NH; ++hh) {
        float a = av[hh] + ev * scal[4 + hh];
        a = (a >= 0.f) ? a : SLOPE * a;
        float exs = expf(a);
        den[hh] = exs;
        acc[hh] = exs * bf2f(hd[hh * 64 + lane]);
    }
    int p0 = start[d], p1 = p0 + dgi;
    for (int p = p0; p < p1; ++p) {
        int s = csrc[p];                                  // wave-uniform broadcast
        float4 e4 = *(const float4*)&cex[(size_t)p * 4];  // broadcast
        const unsigned short* hs = &hbf[(size_t)s * HO];
        den[0] += e4.x; den[1] += e4.y; den[2] += e4.z; den[3] += e4.w;
        acc[0] = fmaf(e4.x, bf2f(hs[lane]), acc[0]);
        acc[1] = fmaf(e4.y, bf2f(hs[64 + lane]), acc[1]);
        acc[2] = fmaf(e4.z, bf2f(hs[128 + lane]), acc[2]);
        acc[3] = fmaf(e4.w, bf2f(hs[192 + lane]), acc[3]);
    }
    float z = 0.25f * (acc[0] / den[0] + acc[1] / den[1] +
                       acc[2] / den[2] + acc[3] / den[3]) + bias[lane];
    z = (z > 0.f) ? z : expm1f(z);
    zall[(size_t)d * 192 + mslice * 64 + lane] = z;
}

// ---------- semantic attention: sem_W column in VGPRs, z via LDS broadcast ----------
__global__ __launch_bounds__(256) void k_semantic(const float* __restrict__ zall,
                                                  const float* __restrict__ semW,
                                                  const float* __restrict__ semb,
                                                  const float* __restrict__ avec,
                                                  float* __restrict__ out) {
    __shared__ float zbuf[4][192];
    int t = threadIdx.x;
    int lane = t & 63;
    int wid = t >> 6;
    float wsc[64];
    #pragma unroll
    for (int k = 0; k < 64; ++k) wsc[k] = semW[k * 64 + lane];
    float sb = semb[lane];
    float av = avec[lane];
    int gw = blockIdx.x * 4 + wid;
    int nwv = gridDim.x * 4;
    for (int n = gw; n < NN; n += nwv) {
        float zm0 = zall[(size_t)n * 192 + lane];
        float zm1 = zall[(size_t)n * 192 + 64 + lane];
        float zm2 = zall[(size_t)n * 192 + 128 + lane];
        zbuf[wid][lane] = zm0;
        zbuf[wid][64 + lane] = zm1;
        zbuf[wid][128 + lane] = zm2;
        float sc3[3];
        #pragma unroll
        for (int m = 0; m < 3; ++m) {
            float a0 = sb, a1 = 0.f, a2 = 0.f, a3 = 0.f;
            #pragma unroll
            for (int k4 = 0; k4 < 16; ++k4) {
                float4 z4 = *(const float4*)&zbuf[wid][m * 64 + k4 * 4];
                a0 = fmaf(z4.x, wsc[k4 * 4 + 0], a0);
                a1 = fmaf(z4.y, wsc[k4 * 4 + 1], a1);
                a2 = fmaf(z4.z, wsc[k4 * 4 + 2], a2);
                a3 = fmaf(z4.w, wsc[k4 * 4 + 3], a3);
            }
            float wg = tanhf((a0 + a1) + (a2 + a3));
            float p = wg * av;
            #pragma unroll
            for (int o = 32; o > 0; o >>= 1) p += __shfl_xor(p, o);
            sc3[m] = p;
        }
        float mx = fmaxf(sc3[0], fmaxf(sc3[1], sc3[2]));
        float e0 = expf(sc3[0] - mx), e1 = expf(sc3[1] - mx), e2 = expf(sc3[2] - mx);
        float inv = 1.f / (e0 + e1 + e2);
        float b0 = e0 * inv, b1 = e1 * inv, b2 = e2 * inv;
        out[(size_t)n * 64 + lane] = b0 * zm0 + b1 * zm1 + b2 * zm2;
        if (lane < 3) {
            float b = (lane == 0) ? b0 : (lane == 1) ? b1 : b2;
            out[(size_t)NN * 64 + (size_t)n * 3 + lane] = b;
        }
    }
}

// ---------- host ----------
extern "C" void kernel_launch(void* const* d_in, const int* in_sizes, int n_in,
                              void* d_out, int out_size, void* d_ws, size_t ws_size,
                              hipStream_t stream) {
    (void)in_sizes; (void)n_in; (void)out_size; (void)ws_size;
    const float* x        = (const float*)d_in[0];
    const int*   ei       = (const int*)d_in[1];
    const float* eattr    = (const float*)d_in[2];
    const float* W        = (const float*)d_in[3];
    const float* att_src  = (const float*)d_in[4];
    const float* att_dst  = (const float*)d_in[5];
    const float* lin_edge = (const float*)d_in[6];
    const float* att_edge = (const float*)d_in[7];
    const float* bias     = (const float*)d_in[8];
    const float* bn_gamma = (const float*)d_in[9];
    const float* bn_beta  = (const float*)d_in[10];
    const float* sem_W    = (const float*)d_in[11];
    const float* sem_b    = (const float*)d_in[12];
    const float* attn_vec = (const float*)d_in[13];
    float* out = (float*)d_out;

    float* ws = (float*)d_ws;
    size_t o = 0;
    unsigned short* hbf = (unsigned short*)(ws + o); o += (size_t)NN * 128;  // 25.6 MB
    float* zall   = ws + o; o += (size_t)NN * 192;   // 38.4 MB
    float* cex    = ws + o; o += (size_t)NE * 4;     //  6.4 MB
    int*   csrc   = (int*)(ws + o); o += (size_t)NE; //  1.6 MB
    float* asn    = ws + o; o += (size_t)NN * 4;
    float* adn    = ws + o; o += (size_t)NN * 4;
    unsigned long long* pk = (unsigned long long*)(ws + o); o += (size_t)NM * NN * 2;  // 8B aligned
    int*   start3 = (int*)(ws + o); o += (size_t)NM * NN;
    int*   rank3  = (int*)(ws + o); o += (size_t)NM * NE;   // per-metapath ranks (race fix)
    float2* part3 = (float2*)(ws + o); o += (size_t)NM * PB * 2;
    float* scal3  = ws + o; o += NM * 16;
    int*   gcur   = (int*)(ws + o); o += 16;
    // total ~80 MB

    k_init<<<((NM * NN) + 255) / 256, 256, 0, stream>>>(pk, gcur);
    k_bn_deg<<<dim3(PB, NM), 256, 0, stream>>>(eattr, ei, pk, rank3, part3);
    k_bn_fin<<<NM, 256, 0, stream>>>(bn_gamma, bn_beta, lin_edge, att_edge, part3, scal3);
    k_offsets<<<dim3((NN + 255) / 256, NM), 256, 0, stream>>>(pk, start3, gcur);

    for (int m = 0; m < NM; ++m) {
        const int* srcA = ei + (size_t)m * 2 * NE;
        const int* dstA = srcA + NE;
        const float* eam = eattr + (size_t)m * NE;

        k_gemm<<<dim3((NN + 63) / 64, NH), 256, 0, stream>>>(
            x, W + (size_t)m * IND * HO,
            att_src + (size_t)m * HO, att_dst + (size_t)m * HO,
            hbf, asn, adn);
        k_scatter<<<(NE + 255) / 256, 256, 0, stream>>>(
            srcA, dstA, eam, scal3 + m * 16, asn, adn,
            start3 + (size_t)m * NN, rank3 + (size_t)m * NE, csrc, cex);
        k_passC<<<((size_t)NN * 64 + 255) / 256, 256, 0, stream>>>(
            start3 + (size_t)m * NN, csrc, cex, hbf, asn, adn,
            pk + (size_t)m * NN, scal3 + m * 16, bias + (size_t)m * 64, zall, m);
    }

    k_semantic<<<2048, 256, 0, stream>>>(zall, sem_W, sem_b, attn_vec, out);
}

// Round 12
// 527.305 us; speedup vs baseline: 2.1051x; 1.4401x over previous
//
#include <hip/hip_runtime.h>
#include <hip/hip_bf16.h>
#include <math.h>

#define NN 50000
#define NE 400000
#define NM 3
#define IND 128
#define OUTD 64
#define NH 4
#define HO 256          // NH*OUTD
#define EPSBN 1e-5f
#define SLOPE 0.2f
#define PB ((NE + 255) / 256)        // partial blocks per metapath = 1563
#define FIXS 8388608.0f              // 2^23 fixed-point scale for asum
#define FIXINV (1.0f / 8388608.0f)
#define PKMASK ((1ULL << 40) - 1ULL)

typedef __attribute__((ext_vector_type(8))) short bf16x8;
typedef __attribute__((ext_vector_type(4))) float f32x4;

// ---------- bf16 helpers (RNE) ----------
__device__ __forceinline__ unsigned short f2bf(float f) {
    unsigned u = __float_as_uint(f);
    unsigned r = (u + 0x7FFFu + ((u >> 16) & 1u)) >> 16;
    return (unsigned short)r;
}
__device__ __forceinline__ float bf2f(unsigned short b) {
    return __uint_as_float(((unsigned)b) << 16);
}

// ---------- init: zero packed deg/asum + global cursors ----------
__global__ __launch_bounds__(256) void k_init(unsigned long long* __restrict__ pk,
                                              int* __restrict__ gcur) {
    size_t i = (size_t)blockIdx.x * blockDim.x + threadIdx.x;
    if (i < (size_t)NM * NN) pk[i] = 0ULL;
    if (i < 16) gcur[i] = 0;
}

// ---------- W -> W^T bf16 (one-shot, tiny: 3x128x256) ----------
__global__ __launch_bounds__(256) void k_wt(const float* __restrict__ W,
                                            unsigned short* __restrict__ Wt) {
    int id = blockIdx.x * 256 + threadIdx.x;
    if (id >= NM * 128 * 256) return;
    int m = id >> 15;
    int rem = id & 32767;
    int k = rem >> 8;      // 0..127
    int c = rem & 255;     // coalesced read along c
    Wt[((size_t)(m * 256 + c) << 7) + k] = f2bf(W[(size_t)(m * 128 + k) * 256 + c]);
}

// ---------- fused: BN partials + packed degree/asum atomic + per-m edge rank ----------
__global__ __launch_bounds__(256) void k_bn_deg(const float* __restrict__ eattr,
                                                const int* __restrict__ ei,
                                                unsigned long long* __restrict__ pk,
                                                int* __restrict__ rank3,
                                                float2* __restrict__ part3) {
    int m = blockIdx.y;
    int e = blockIdx.x * blockDim.x + threadIdx.x;
    float s1 = 0.f, s2 = 0.f;
    if (e < NE) {
        const float* ea = eattr + (size_t)m * NE;
        const int* dst = ei + (size_t)m * 2 * NE + NE;
        float v = log1pf(ea[e]);
        int d = dst[e];
        unsigned long long inc = (1ULL << 40) +
            (unsigned long long)(v * FIXS + 0.5f);
        unsigned long long old = atomicAdd(&pk[(size_t)m * NN + d], inc);
        rank3[(size_t)m * NE + e] = (int)(old >> 40);   // rank among same-dst edges, PER m
        s1 = v; s2 = v * v;
    }
    #pragma unroll
    for (int o = 32; o > 0; o >>= 1) {
        s1 += __shfl_down(s1, o);
        s2 += __shfl_down(s2, o);
    }
    __shared__ float ls1[4], ls2[4];
    int t = threadIdx.x;
    if ((t & 63) == 0) { ls1[t >> 6] = s1; ls2[t >> 6] = s2; }
    __syncthreads();
    if (t == 0) {
        float a = (ls1[0] + ls1[1]) + (ls1[2] + ls1[3]);
        float b = (ls2[0] + ls2[1]) + (ls2[2] + ls2[3]);
        part3[(size_t)m * PB + blockIdx.x] = make_float2(a, b);
    }
}

// ---------- finalize BN scale/shift + edge-attention dot products ----------
__global__ __launch_bounds__(256) void k_bn_fin(const float* __restrict__ gamma,
                                                const float* __restrict__ beta,
                                                const float* __restrict__ lin_edge,
                                                const float* __restrict__ att_edge,
                                                const float2* __restrict__ part3,
                                                float* __restrict__ scal3) {
    int m = blockIdx.x;
    int t = threadIdx.x;
    float* scal = scal3 + m * 16;
    const float2* part = part3 + (size_t)m * PB;
    float s1 = 0.f, s2 = 0.f;
    for (int i = t; i < PB; i += 256) {
        float2 p = part[i];
        s1 += p.x; s2 += p.y;
    }
    #pragma unroll
    for (int o = 32; o > 0; o >>= 1) {
        s1 += __shfl_down(s1, o);
        s2 += __shfl_down(s2, o);
    }
    __shared__ float ls1[4], ls2[4];
    if ((t & 63) == 0) { ls1[t >> 6] = s1; ls2[t >> 6] = s2; }
    __syncthreads();
    if (t == 0) {
        float su = (ls1[0] + ls1[1]) + (ls1[2] + ls1[3]);
        float sq = (ls2[0] + ls2[1]) + (ls2[2] + ls2[3]);
        float mu = su / (float)NE;
        float var = sq / (float)NE - mu * mu;
        float sc = gamma[m] * rsqrtf(var + EPSBN);
        scal[2] = sc;
        scal[3] = beta[m] - mu * sc;
    }
    if (t < 4) {
        const float* le = lin_edge + (size_t)m * HO;
        const float* ae = att_edge + (size_t)m * HO;
        float acc = 0.f;
        for (int c = 0; c < 64; ++c)
            acc += le[t * 64 + c] * ae[t * 64 + c];
        scal[4 + t] = acc;
    }
}

// ---------- parallel range allocator (unordered disjoint CSR ranges) ----------
__global__ __launch_bounds__(256) void k_offsets(const unsigned long long* __restrict__ pk,
                                                 int* __restrict__ start3,
                                                 int* __restrict__ gcur) {
    int m = blockIdx.y;
    int i = blockIdx.x * blockDim.x + threadIdx.x;   // node id
    int lane = threadIdx.x & 63;
    int d = (i < NN) ? (int)(pk[(size_t)m * NN + i] >> 40) : 0;
    int inc = d;
    #pragma unroll
    for (int o = 1; o < 64; o <<= 1) {
        int v = __shfl_up(inc, o);
        if (lane >= o) inc += v;
    }
    int total = __shfl(inc, 63);
    int base = 0;
    if (lane == 63 && total > 0) base = atomicAdd(&gcur[m], total);
    base = __shfl(base, 63);
    if (i < NN) start3[(size_t)m * NN + i] = base + inc - d;
}

// ---------- MFMA GEMM: h(bf16) = x @ W[m], fused a_src/a_dst epilogue ----------
// Block: 64 rows x 128 cols (2 heads). 4 waves; wave w owns rows 16w..16w+15.
// A = x row-major -> As[row][k] bf16 (no transpose). B from pre-transposed Wt[col][k].
__global__ __launch_bounds__(256) void k_gemm_mfma(const float* __restrict__ x,
                                                   const unsigned short* __restrict__ Wtm,
                                                   const float* __restrict__ att_s,
                                                   const float* __restrict__ att_d,
                                                   unsigned short* __restrict__ hbf,
                                                   float* __restrict__ asn,
                                                   float* __restrict__ adn) {
    __shared__ unsigned short As[64 * 136];    // stride 136 bf16 = 272 B (16B-aligned)
    __shared__ unsigned short Bs[128 * 136];
    int t = threadIdx.x;
    int row0 = blockIdx.x * 64;
    int cb = blockIdx.y;                       // col-block: heads 2cb, 2cb+1

    // stage A: 64x128 f32 -> bf16, coalesced float4 loads, contiguous 8B LDS writes
    #pragma unroll
    for (int i = 0; i < 8; ++i) {
        int e = i * 256 + t;
        int r = e >> 5, c4 = e & 31;
        float4 v = make_float4(0.f, 0.f, 0.f, 0.f);
        if (row0 + r < NN) v = *(const float4*)&x[(size_t)(row0 + r) * IND + c4 * 4];
        unsigned u0 = (unsigned)f2bf(v.x) | ((unsigned)f2bf(v.y) << 16);
        unsigned u1 = (unsigned)f2bf(v.z) | ((unsigned)f2bf(v.w) << 16);
        *(uint2*)&As[r * 136 + c4 * 4] = make_uint2(u0, u1);
    }
    // stage B: Wt[col][k] bf16 -> LDS, contiguous 16B copies
    #pragma unroll
    for (int i = 0; i < 8; ++i) {
        int e = i * 256 + t;
        int col = e >> 4, k8 = e & 15;
        *(bf16x8*)&Bs[col * 136 + k8 * 8] =
            *(const bf16x8*)&Wtm[(size_t)(cb * 128 + col) * 128 + k8 * 8];
    }
    __syncthreads();

    int a = t & 15, c = (t >> 4) & 3, w = t >> 6;
    // A fragments: lane holds row (16w+a), k = 32*ks + 8*c + j
    bf16x8 af[4];
    #pragma unroll
    for (int ks = 0; ks < 4; ++ks)
        af[ks] = *(const bf16x8*)&As[(16 * w + a) * 136 + ks * 32 + c * 8];

    f32x4 acc[8];
    #pragma unroll
    for (int ct = 0; ct < 8; ++ct) acc[ct] = (f32x4){0.f, 0.f, 0.f, 0.f};
    #pragma unroll
    for (int ct = 0; ct < 8; ++ct) {
        #pragma unroll
        for (int ks = 0; ks < 4; ++ks) {
            bf16x8 bf = *(const bf16x8*)&Bs[(ct * 16 + a) * 136 + ks * 32 + c * 8];
            acc[ct] = __builtin_amdgcn_mfma_f32_16x16x32_bf16(af[ks], bf, acc[ct], 0, 0, 0);
        }
    }

    // epilogue: C/D layout col = lane&15 (= a), row = 4*(lane>>4) + reg = 4c + reg
    float as_c[8], ad_c[8];
    #pragma unroll
    for (int ct = 0; ct < 8; ++ct) {
        as_c[ct] = att_s[cb * 128 + ct * 16 + a];
        ad_c[ct] = att_d[cb * 128 + ct * 16 + a];
    }
    #pragma unroll
    for (int reg = 0; reg < 4; ++reg) {
        int row = row0 + 16 * w + 4 * c + reg;
        bool ok = row < NN;
        #pragma unroll
        for (int ct = 0; ct < 8; ++ct)
            if (ok) hbf[(size_t)row * HO + cb * 128 + ct * 16 + a] = f2bf(acc[ct][reg]);
        float s0 = 0.f, s1 = 0.f, d0 = 0.f, d1 = 0.f;
        #pragma unroll
        for (int ct = 0; ct < 4; ++ct) {
            s0 += acc[ct][reg] * as_c[ct];
            d0 += acc[ct][reg] * ad_c[ct];
            s1 += acc[ct + 4][reg] * as_c[ct + 4];
            d1 += acc[ct + 4][reg] * ad_c[ct + 4];
        }
        #pragma unroll
        for (int o = 8; o > 0; o >>= 1) {
            s0 += __shfl_xor(s0, o, 16);
            s1 += __shfl_xor(s1, o, 16);
            d0 += __shfl_xor(d0, o, 16);
            d1 += __shfl_xor(d1, o, 16);
        }
        if (a == 0 && ok) {
            asn[row * 4 + 2 * cb]     = s0;
            asn[row * 4 + 2 * cb + 1] = s1;
            adn[row * 4 + 2 * cb]     = d0;
            adn[row * 4 + 2 * cb + 1] = d1;
        }
    }
}

// ---------- scatter: alpha -> exp(alpha), slot = start[d] + rank[e], NO atomics ----------
__global__ __launch_bounds__(256) void k_scatter(const int* __restrict__ srcA,
                                                 const int* __restrict__ dstA,
                                                 const float* __restrict__ ea,
                                                 const float* __restrict__ scal,
                                                 const float* __restrict__ asn,
                                                 const float* __restrict__ adn,
                                                 const int* __restrict__ start,
                                                 const int* __restrict__ rank,
                                                 int* __restrict__ csrc,
                                                 float* __restrict__ cex) {
    int e = blockIdx.x * blockDim.x + threadIdx.x;
    if (e >= NE) return;
    int s = srcA[e], d = dstA[e];
    float ev = log1pf(ea[e]) * scal[2] + scal[3];
    float4 as4 = *(const float4*)&asn[s * 4];
    float4 ad4 = *(const float4*)&adn[d * 4];
    float av[4] = {as4.x + ad4.x, as4.y + ad4.y, as4.z + ad4.z, as4.w + ad4.w};
    float ex[4];
    #pragma unroll
    for (int hh = 0; hh < NH; ++hh) {
        float a = av[hh] + ev * scal[4 + hh];
        a = (a >= 0.f) ? a : SLOPE * a;
        ex[hh] = expf(a);
    }
    int pos = start[d] + rank[e];
    csrc[pos] = s;
    *(float4*)&cex[(size_t)pos * 4] = make_float4(ex[0], ex[1], ex[2], ex[3]);
}

// ---------- pass C: wave per destination, register accumulate, no atomics ----------
__global__ __launch_bounds__(256) void k_passC(const int* __restrict__ start,
                                               const int* __restrict__ csrc,
                                               const float* __restrict__ cex,
                                               const unsigned short* __restrict__ hbf,
                                               const float* __restrict__ asn,
                                               const float* __restrict__ adn,
                                               const unsigned long long* __restrict__ pk,
                                               const float* __restrict__ scal,
                                               const float* __restrict__ bias,
                                               float* __restrict__ zall,
                                               int mslice) {
    int lane = threadIdx.x & 63;
    int d = (int)((blockIdx.x * (size_t)blockDim.x + threadIdx.x) >> 6);
    if (d >= NN) return;
    unsigned long long pkd = pk[d];
    int dgi = (int)(pkd >> 40);
    float asum = (float)(pkd & PKMASK) * FIXINV;
    float4 as4 = *(const float4*)&asn[d * 4];
    float4 ad4 = *(const float4*)&adn[d * 4];
    float ev = (dgi > 0) ? (asum / (float)dgi) * scal[2] + scal[3] : 0.f;
    float av[4] = {as4.x + ad4.x, as4.y + ad4.y, as4.z + ad4.z, as4.w + ad4.w};
    float den[4], acc[4];
    const unsigned short* hd = &hbf[(size_t)d * HO];
    #pragma unroll
    for (int hh = 0; hh < NH; ++hh) {
        float a = av[hh] + ev * scal[4 + hh];
        a = (a >= 0.f) ? a : SLOPE * a;
        float exs = expf(a);
        den[hh] = exs;
        acc[hh] = exs * bf2f(hd[hh * 64 + lane]);
    }
    int p0 = start[d], p1 = p0 + dgi;
    for (int p = p0; p < p1; ++p) {
        int s = csrc[p];                                  // wave-uniform broadcast
        float4 e4 = *(const float4*)&cex[(size_t)p * 4];  // broadcast
        const unsigned short* hs = &hbf[(size_t)s * HO];
        den[0] += e4.x; den[1] += e4.y; den[2] += e4.z; den[3] += e4.w;
        acc[0] = fmaf(e4.x, bf2f(hs[lane]), acc[0]);
        acc[1] = fmaf(e4.y, bf2f(hs[64 + lane]), acc[1]);
        acc[2] = fmaf(e4.z, bf2f(hs[128 + lane]), acc[2]);
        acc[3] = fmaf(e4.w, bf2f(hs[192 + lane]), acc[3]);
    }
    float z = 0.25f * (acc[0] / den[0] + acc[1] / den[1] +
                       acc[2] / den[2] + acc[3] / den[3]) + bias[lane];
    z = (z > 0.f) ? z : expm1f(z);
    zall[(size_t)d * 192 + mslice * 64 + lane] = z;
}

// ---------- semantic attention: sem_W column in VGPRs, z via LDS broadcast ----------
__global__ __launch_bounds__(256) void k_semantic(const float* __restrict__ zall,
                                                  const float* __restrict__ semW,
                                                  const float* __restrict__ semb,
                                                  const float* __restrict__ avec,
                                                  float* __restrict__ out) {
    __shared__ float zbuf[4][192];
    int t = threadIdx.x;
    int lane = t & 63;
    int wid = t >> 6;
    float wsc[64];
    #pragma unroll
    for (int k = 0; k < 64; ++k) wsc[k] = semW[k * 64 + lane];
    float sb = semb[lane];
    float av = avec[lane];
    int gw = blockIdx.x * 4 + wid;
    int nwv = gridDim.x * 4;
    for (int n = gw; n < NN; n += nwv) {
        float zm0 = zall[(size_t)n * 192 + lane];
        float zm1 = zall[(size_t)n * 192 + 64 + lane];
        float zm2 = zall[(size_t)n * 192 + 128 + lane];
        zbuf[wid][lane] = zm0;
        zbuf[wid][64 + lane] = zm1;
        zbuf[wid][128 + lane] = zm2;
        float sc3[3];
        #pragma unroll
        for (int m = 0; m < 3; ++m) {
            float a0 = sb, a1 = 0.f, a2 = 0.f, a3 = 0.f;
            #pragma unroll
            for (int k4 = 0; k4 < 16; ++k4) {
                float4 z4 = *(const float4*)&zbuf[wid][m * 64 + k4 * 4];
                a0 = fmaf(z4.x, wsc[k4 * 4 + 0], a0);
                a1 = fmaf(z4.y, wsc[k4 * 4 + 1], a1);
                a2 = fmaf(z4.z, wsc[k4 * 4 + 2], a2);
                a3 = fmaf(z4.w, wsc[k4 * 4 + 3], a3);
            }
            float wg = tanhf((a0 + a1) + (a2 + a3));
            float p = wg * av;
            #pragma unroll
            for (int o = 32; o > 0; o >>= 1) p += __shfl_xor(p, o);
            sc3[m] = p;
        }
        float mx = fmaxf(sc3[0], fmaxf(sc3[1], sc3[2]));
        float e0 = expf(sc3[0] - mx), e1 = expf(sc3[1] - mx), e2 = expf(sc3[2] - mx);
        float inv = 1.f / (e0 + e1 + e2);
        float b0 = e0 * inv, b1 = e1 * inv, b2 = e2 * inv;
        out[(size_t)n * 64 + lane] = b0 * zm0 + b1 * zm1 + b2 * zm2;
        if (lane < 3) {
            float b = (lane == 0) ? b0 : (lane == 1) ? b1 : b2;
            out[(size_t)NN * 64 + (size_t)n * 3 + lane] = b;
        }
    }
}

// ---------- host ----------
extern "C" void kernel_launch(void* const* d_in, const int* in_sizes, int n_in,
                              void* d_out, int out_size, void* d_ws, size_t ws_size,
                              hipStream_t stream) {
    (void)in_sizes; (void)n_in; (void)out_size; (void)ws_size;
    const float* x        = (const float*)d_in[0];
    const int*   ei       = (const int*)d_in[1];
    const float* eattr    = (const float*)d_in[2];
    const float* W        = (const float*)d_in[3];
    const float* att_src  = (const float*)d_in[4];
    const float* att_dst  = (const float*)d_in[5];
    const float* lin_edge = (const float*)d_in[6];
    const float* att_edge = (const float*)d_in[7];
    const float* bias     = (const float*)d_in[8];
    const float* bn_gamma = (const float*)d_in[9];
    const float* bn_beta  = (const float*)d_in[10];
    const float* sem_W    = (const float*)d_in[11];
    const float* sem_b    = (const float*)d_in[12];
    const float* attn_vec = (const float*)d_in[13];
    float* out = (float*)d_out;

    float* ws = (float*)d_ws;
    size_t o = 0;
    unsigned short* hbf = (unsigned short*)(ws + o); o += (size_t)NN * 128;  // 25.6 MB
    unsigned short* wtb = (unsigned short*)(ws + o); o += (size_t)NM * 256 * 64;  // 196KB bf16 W^T
    float* zall   = ws + o; o += (size_t)NN * 192;   // 38.4 MB
    float* cex    = ws + o; o += (size_t)NE * 4;     //  6.4 MB
    int*   csrc   = (int*)(ws + o); o += (size_t)NE; //  1.6 MB
    float* asn    = ws + o; o += (size_t)NN * 4;
    float* adn    = ws + o; o += (size_t)NN * 4;
    unsigned long long* pk = (unsigned long long*)(ws + o); o += (size_t)NM * NN * 2;  // 8B aligned
    int*   start3 = (int*)(ws + o); o += (size_t)NM * NN;
    int*   rank3  = (int*)(ws + o); o += (size_t)NM * NE;   // per-metapath ranks
    float2* part3 = (float2*)(ws + o); o += (size_t)NM * PB * 2;
    float* scal3  = ws + o; o += NM * 16;
    int*   gcur   = (int*)(ws + o); o += 16;
    // total ~81 MB

    k_init<<<((NM * NN) + 255) / 256, 256, 0, stream>>>(pk, gcur);
    k_wt<<<(NM * 128 * 256 + 255) / 256, 256, 0, stream>>>(W, wtb);
    k_bn_deg<<<dim3(PB, NM), 256, 0, stream>>>(eattr, ei, pk, rank3, part3);
    k_bn_fin<<<NM, 256, 0, stream>>>(bn_gamma, bn_beta, lin_edge, att_edge, part3, scal3);
    k_offsets<<<dim3((NN + 255) / 256, NM), 256, 0, stream>>>(pk, start3, gcur);

    for (int m = 0; m < NM; ++m) {
        const int* srcA = ei + (size_t)m * 2 * NE;
        const int* dstA = srcA + NE;
        const float* eam = eattr + (size_t)m * NE;

        k_gemm_mfma<<<dim3((NN + 63) / 64, 2), 256, 0, stream>>>(
            x, wtb + (size_t)m * 256 * 128,
            att_src + (size_t)m * HO, att_dst + (size_t)m * HO,
            hbf, asn, adn);
        k_scatter<<<(NE + 255) / 256, 256, 0, stream>>>(
            srcA, dstA, eam, scal3 + m * 16, asn, adn,
            start3 + (size_t)m * NN, rank3 + (size_t)m * NE, csrc, cex);
        k_passC<<<((size_t)NN * 64 + 255) / 256, 256, 0, stream>>>(
            start3 + (size_t)m * NN, csrc, cex, hbf, asn, adn,
            pk + (size_t)m * NN, scal3 + m * 16, bias + (size_t)m * 64, zall, m);
    }

    k_semantic<<<2048, 256, 0, stream>>>(zall, sem_W, sem_b, attn_vec, out);
}